// Round 12
// baseline (59.371 us; speedup 1.0000x reference)
//
#include <hip/hip_runtime.h>
#include <hip/hip_bf16.h>
#include <math.h>

#define N_NODES 20000
#define N_EDGES 640000
#define D 128

#define BSHIFT 4
#define BNODES 16                 // nodes per bucket
#define NB 1250                   // N_NODES >> BSHIFT (exact: 1250*16 = 20000)
#define CAP2 768                  // per-bucket cap (mean 512, sd ~22.6)
#define AGG_T 512
#define NBLK1 160
#define CHUNK 4000                // N_EDGES / NBLK1, multiple of 4
#define GPAD 16                   // gcur padded to one 64B line per bucket
#define CASTBLK 2500              // ceil(N_NODES*D/4 / 256)

#define GROWS 16                  // fallback linear kernel

typedef __attribute__((ext_vector_type(8))) short bf16x8;
typedef __attribute__((ext_vector_type(4))) float f32x4;

static __device__ __forceinline__ unsigned short f2bf(float f) {
  unsigned u = __float_as_uint(f);
  return (unsigned short)((u + 0x7fffu + ((u >> 16) & 1u)) >> 16);
}
static __device__ __forceinline__ float bflo(unsigned v) {
  return __uint_as_float(v << 16);
}
static __device__ __forceinline__ float bfhi(unsigned v) {
  return __uint_as_float(v & 0xffff0000u);
}

__global__ __launch_bounds__(256) void zero_kernel(int* __restrict__ p, int n) {
  const int i = blockIdx.x * 256 + threadIdx.x;
  if (i < n) p[i] = 0;
}

// ---- fused: blocks [0,NBLK1) bin via LDS counting sort into 1250 sub-buckets;
//      blocks [NBLK1,..) cast x,W to bf16 ----
__global__ __launch_bounds__(256) void castbin_kernel(
    const float* __restrict__ x, const float* __restrict__ W,
    const int* __restrict__ rows, const int* __restrict__ cols,
    const float* __restrict__ ew,
    unsigned* __restrict__ xb, unsigned* __restrict__ Wb,
    int* __restrict__ gcur, uint2* __restrict__ bins) {
  __shared__ uint2 stage[CHUNK];   // 32 KB sorted staging
  __shared__ int cnt[NB];          // 5 KB
  __shared__ int lbase[NB];        // 5 KB
  __shared__ int gbase[NB];        // 5 KB
  const int tid = threadIdx.x;
  if (blockIdx.x < NBLK1) {
    // ---- bin: count -> scan -> LDS rank-scatter -> coalesced write-out ----
    const int e0 = blockIdx.x * CHUNK;
    for (int i = tid; i < NB; i += 256) cnt[i] = 0;
    __syncthreads();
    const int4* r4 = reinterpret_cast<const int4*>(rows + e0);
    for (int t = tid; t < CHUNK / 4; t += 256) {
      const int4 rv = r4[t];
      atomicAdd(&cnt[rv.x >> BSHIFT], 1);
      atomicAdd(&cnt[rv.y >> BSHIFT], 1);
      atomicAdd(&cnt[rv.z >> BSHIFT], 1);
      atomicAdd(&cnt[rv.w >> BSHIFT], 1);
    }
    __syncthreads();
    if (tid < 64) {  // single-wave serial-carry scan over 1250 counters
      int carry = 0;
      for (int c0 = 0; c0 < NB; c0 += 64) {
        const int idx = c0 + tid;
        const int v = (idx < NB) ? cnt[idx] : 0;
        int s = v;
#pragma unroll
        for (int off = 1; off < 64; off <<= 1) {
          const int t = __shfl_up(s, off);
          if (tid >= off) s += t;
        }
        if (idx < NB) lbase[idx] = carry + s - v;
        carry += __shfl(s, 63);
      }
    }
    for (int i = tid; i < NB; i += 256) {
      const int c = cnt[i];
      gbase[i] = c ? atomicAdd(&gcur[i * GPAD], c) : 0;  // one line per bucket
    }
    __syncthreads();
    for (int i = tid; i < NB; i += 256) cnt[i] = 0;
    __syncthreads();
    for (int t = tid; t < CHUNK / 4; t += 256) {  // rank-scatter into LDS
      const int4 rv = r4[t];
      const int4 cv = reinterpret_cast<const int4*>(cols + e0)[t];
      const float4 wv = reinterpret_cast<const float4*>(ew + e0)[t];
      const int rr[4] = {rv.x, rv.y, rv.z, rv.w};
      const int cc[4] = {cv.x, cv.y, cv.z, cv.w};
      const float ww[4] = {wv.x, wv.y, wv.z, wv.w};
#pragma unroll
      for (int u = 0; u < 4; ++u) {
        const int b = rr[u] >> BSHIFT;
        const int r = atomicAdd(&cnt[b], 1);
        stage[lbase[b] + r] =  // < CHUNK by construction
            make_uint2(((unsigned)rr[u] << 16) | (unsigned)cc[u],
                       __float_as_uint(ww[u]));
      }
    }
    __syncthreads();
    // write-out: adjacent lanes -> adjacent slots -> coalesced bucket runs
    for (int i = tid; i < CHUNK; i += 256) {
      const uint2 e = stage[i];
      const int b = (int)(e.x >> 20);  // row>>4
      const int p = gbase[b] + (i - lbase[b]);
      if (p < CAP2) bins[(size_t)b * CAP2 + p] = e;
    }
  } else {
    // ---------------- cast ----------------
    const int i = (blockIdx.x - NBLK1) * 256 + tid;
    if (i < N_NODES * D / 4) {
      const float4 v = *reinterpret_cast<const float4*>(&x[(size_t)i * 4]);
      uint2 o;
      o.x = (unsigned)f2bf(v.x) | ((unsigned)f2bf(v.y) << 16);
      o.y = (unsigned)f2bf(v.z) | ((unsigned)f2bf(v.w) << 16);
      *reinterpret_cast<uint2*>(&xb[(size_t)i * 2]) = o;
    }
    if (i < D * D / 4) {
      const float4 v = *reinterpret_cast<const float4*>(&W[(size_t)i * 4]);
      uint2 o;
      o.x = (unsigned)f2bf(v.x) | ((unsigned)f2bf(v.y) << 16);
      o.y = (unsigned)f2bf(v.z) | ((unsigned)f2bf(v.w) << 16);
      *reinterpret_cast<uint2*>(&Wb[(size_t)i * 2]) = o;
    }
  }
}

// ---- fused agg+gemm, one block per 16-node bucket, 1250 blocks ----
__global__ __launch_bounds__(AGG_T) void agg_gemm_kernel(
    const unsigned* __restrict__ xb, const int* __restrict__ gcur,
    const uint2* __restrict__ bins, const unsigned* __restrict__ Wb,
    const float* __restrict__ bias, float* __restrict__ out) {
  __shared__ uint2 list[CAP2];             // 6 KB
  __shared__ unsigned aggls[BNODES * 64];  // 4 KB, swizzled bf16 means
  __shared__ int cnt[BNODES];
  __shared__ int base[BNODES];
  __shared__ float degls[BNODES];
  const int b = blockIdx.x;
  const int tid = threadIdx.x;
  const int n = min(gcur[b * GPAD], CAP2);
  if (tid < BNODES) cnt[tid] = 0;
  __syncthreads();

  // rank edges by local node id; uint4 load = 2 edges per thread (covers 1024>=768)
  uint2 e0v, e1v;
  int rk0 = -1, rk1 = -1, rl0 = 0, rl1 = 0;
  {
    const int i0 = tid * 2;
    if (i0 < n) {
      const uint4 p = *reinterpret_cast<const uint4*>(&bins[(size_t)b * CAP2 + i0]);
      e0v = make_uint2(p.x, p.y);
      rl0 = (int)(p.x >> 16) & 15;
      rk0 = atomicAdd(&cnt[rl0], 1);
      if (i0 + 1 < n) {
        e1v = make_uint2(p.z, p.w);
        rl1 = (int)(p.z >> 16) & 15;
        rk1 = atomicAdd(&cnt[rl1], 1);
      }
    }
  }
  __syncthreads();
  if (tid < 64) {  // wave-parallel inclusive scan over 16 counters
    const int c = (tid < BNODES) ? cnt[tid] : 0;
    int s = c;
#pragma unroll
    for (int off = 1; off < BNODES; off <<= 1) {
      const int t = __shfl_up(s, off);
      if (tid >= off) s += t;
    }
    if (tid < BNODES) base[tid] = s - c;
  }
  __syncthreads();
  if (rk0 >= 0) list[base[rl0] + rk0] = e0v;
  if (rk1 >= 0) list[base[rl1] + rk1] = e1v;
  __syncthreads();

  // gather: 8 waves x 2 nodes; lane = (quarter q4, fidx); lane loads uint4 =
  // feats 8f..8f+7 of edge (k + u*4 + q4): one wave-load covers 4 edges (1 KB).
  const int wv = tid >> 6, lane = tid & 63;
  const int q4 = lane >> 4, fidx = lane & 15;
  for (int q = 0; q < 2; ++q) {
    const int rl = wv * 2 + q;
    const int s = base[rl];
    const int ke = s + cnt[rl];
    float a[8] = {0.f, 0.f, 0.f, 0.f, 0.f, 0.f, 0.f, 0.f};
    float dw = 0.f;
    for (int k = s; k < ke; k += 32) {  // 32 edges in flight per wave
      uint4 v[8];
      float w[8];
#pragma unroll
      for (int u = 0; u < 8; ++u) {
        int idx = k + u * 4 + q4;
        const bool ok = idx < ke;
        if (!ok) idx = ke - 1;          // loop entered => ke >= s+1, safe
        const uint2 e = list[idx];
        w[u] = ok ? __uint_as_float(e.y) : 0.f;
        v[u] = *reinterpret_cast<const uint4*>(
            &xb[(size_t)(e.x & 0xffffu) * (D / 2) + fidx * 4]);
      }
#pragma unroll
      for (int u = 0; u < 8; ++u) {
        a[0] += bflo(v[u].x) * w[u]; a[1] += bfhi(v[u].x) * w[u];
        a[2] += bflo(v[u].y) * w[u]; a[3] += bfhi(v[u].y) * w[u];
        a[4] += bflo(v[u].z) * w[u]; a[5] += bfhi(v[u].z) * w[u];
        a[6] += bflo(v[u].w) * w[u]; a[7] += bfhi(v[u].w) * w[u];
        dw += w[u];
      }
    }
    // combine the 4 quarters
#pragma unroll
    for (int j = 0; j < 8; ++j) {
      a[j] += __shfl_xor(a[j], 16);
      a[j] += __shfl_xor(a[j], 32);
    }
    dw += __shfl_xor(dw, 16);
    dw += __shfl_xor(dw, 32);
    const float dinv = dw > 0.f ? 1.f / dw : 0.f;
    if (lane == 0) degls[rl] = dw;
    if (q4 == 0) {  // lanes 0-15 store the mean, swizzled, uint4 (16B aligned)
      uint4 o;
      o.x = (unsigned)f2bf(a[0] * dinv) | ((unsigned)f2bf(a[1] * dinv) << 16);
      o.y = (unsigned)f2bf(a[2] * dinv) | ((unsigned)f2bf(a[3] * dinv) << 16);
      o.z = (unsigned)f2bf(a[4] * dinv) | ((unsigned)f2bf(a[5] * dinv) << 16);
      o.w = (unsigned)f2bf(a[6] * dinv) | ((unsigned)f2bf(a[7] * dinv) << 16);
      *reinterpret_cast<uint4*>(
          &aggls[rl * 64 + ((fidx * 4) ^ ((rl & 7) << 2))]) = o;
    }
  }
  __syncthreads();

  // GEMM + normalize: wave 0 only, 16-row tile (R7-verified body)
  if (wv != 0) return;
  const int arow = lane & 15;               // local row 0..15
  const int koff = (lane >> 4) * 4;

  bf16x8 afr[4];
#pragma unroll
  for (int kk = 0; kk < 4; ++kk) {
    const int wbase = (kk * 16 + koff) ^ ((arow & 7) << 2);
    union { uint4 u; bf16x8 v; } cv;
    cv.u = *reinterpret_cast<const uint4*>(&aggls[arow * 64 + wbase]);
    afr[kk] = cv.v;
  }

  f32x4 acc[8];
#pragma unroll
  for (int t = 0; t < 8; ++t) {
    const int o = t * 16 + (lane & 15);
    f32x4 c = {0.f, 0.f, 0.f, 0.f};
#pragma unroll
    for (int kk = 0; kk < 4; ++kk) {
      union { uint4 u; bf16x8 v; } cv;
      cv.u = *reinterpret_cast<const uint4*>(
          &Wb[(size_t)o * (D / 2) + kk * 16 + koff]);
      c = __builtin_amdgcn_mfma_f32_16x16x32_bf16(afr[kk], cv.v, c, 0, 0, 0);
    }
    acc[t] = c;
  }

  float ss[4] = {0.f, 0.f, 0.f, 0.f};
#pragma unroll
  for (int t = 0; t < 8; ++t) {
    const float bc = bias[t * 16 + (lane & 15)];
#pragma unroll
    for (int r = 0; r < 4; ++r) {
      const float y = acc[t][r] + bc;
      acc[t][r] = y;
      ss[r] += y * y;
    }
  }
#pragma unroll
  for (int r = 0; r < 4; ++r) {
#pragma unroll
    for (int off = 1; off < 16; off <<= 1)
      ss[r] += __shfl_xor(ss[r], off);
  }
  const int row0 = b * BNODES;
  float scale[4];
#pragma unroll
  for (int r = 0; r < 4; ++r) {
    const int lrow = (lane >> 4) * 4 + r;
    const float dw = degls[lrow];
    scale[r] = (dw > 0.f) ? 1.f / fmaxf(sqrtf(ss[r]), 1e-12f) : 0.f;
  }
#pragma unroll
  for (int t = 0; t < 8; ++t) {
#pragma unroll
    for (int r = 0; r < 4; ++r) {
      const int lrow = (lane >> 4) * 4 + r;
      out[(size_t)(row0 + lrow) * D + t * 16 + (lane & 15)] =
          acc[t][r] * scale[r];
    }
  }
}

// ---- fallback path (tiny ws): f32 scatter + f32 GEMV/norm ----
__global__ __launch_bounds__(256) void scatter_kernel(
    const float* __restrict__ x, const int* __restrict__ rows,
    const int* __restrict__ cols, const float* __restrict__ ew,
    float* __restrict__ out, float* __restrict__ degw) {
  const int e = blockIdx.x * 4 + (threadIdx.x >> 6);
  const int lane = threadIdx.x & 63;
  if (e >= N_EDGES) return;
  const int r = rows[e];
  const int c = cols[e];
  const float w = ew[e];
  const float2 v = *reinterpret_cast<const float2*>(&x[(size_t)c * D + lane * 2]);
  atomicAdd(&out[(size_t)r * D + lane * 2], v.x * w);
  atomicAdd(&out[(size_t)r * D + lane * 2 + 1], v.y * w);
  if (lane == 0) atomicAdd(&degw[r], w);
}

__global__ __launch_bounds__(256) void linear_norm_kernel(
    const float* __restrict__ W, const float* __restrict__ b,
    const float* __restrict__ degw, float* __restrict__ out) {
  __shared__ float Ws[D][D + 1];
  __shared__ float xs[GROWS][D];
  __shared__ float dws[GROWS];
  const int tid = threadIdx.x;
  const int row0 = blockIdx.x * GROWS;
  for (int idx = tid; idx < D * D; idx += 256)
    Ws[idx >> 7][idx & 127] = W[idx];
  if (tid < GROWS) dws[tid] = degw[row0 + tid];
  __syncthreads();
  for (int idx = tid; idx < GROWS * D; idx += 256) {
    const int r = idx >> 7;
    const float dw = dws[r];
    const float dinv = dw > 0.f ? 1.f / dw : 0.f;
    xs[r][idx & 127] = out[(size_t)(row0 + r) * D + (idx & 127)] * dinv;
  }
  __syncthreads();
  const int o = tid & 127;
  const int rh = tid >> 7;
  float acc[GROWS / 2];
#pragma unroll
  for (int j = 0; j < GROWS / 2; ++j) acc[j] = 0.f;
  for (int k = 0; k < D; ++k) {
    const float wv = Ws[o][k];
#pragma unroll
    for (int j = 0; j < GROWS / 2; ++j)
      acc[j] += xs[rh + 2 * j][k] * wv;
  }
  const float bias = b[o];
  __syncthreads();
#pragma unroll
  for (int j = 0; j < GROWS / 2; ++j)
    xs[rh + 2 * j][o] = acc[j] + bias;
  __syncthreads();
  const int w = tid >> 6, lane = tid & 63;
#pragma unroll
  for (int q = 0; q < 4; ++q) {
    const int r = w * 4 + q;
    const float2 v = *reinterpret_cast<const float2*>(&xs[r][lane * 2]);
    float ss = v.x * v.x + v.y * v.y;
#pragma unroll
    for (int off = 1; off < 64; off <<= 1) ss += __shfl_xor(ss, off);
    const float dw = dws[r];
    const float scale = (dw > 0.f) ? 1.f / fmaxf(sqrtf(ss), 1e-12f) : 0.f;
    *reinterpret_cast<float2*>(&out[(size_t)(row0 + r) * D + lane * 2]) =
        make_float2(v.x * scale, v.y * scale);
  }
}

extern "C" void kernel_launch(void* const* d_in, const int* in_sizes, int n_in,
                              void* d_out, int out_size, void* d_ws, size_t ws_size,
                              hipStream_t stream) {
  const float* x  = (const float*)d_in[0];
  const int*   ei = (const int*)d_in[1];
  const float* ew = (const float*)d_in[2];
  const float* W  = (const float*)d_in[3];
  const float* b  = (const float*)d_in[4];
  float* out = (float*)d_out;
  char* ws = (char*)d_ws;

  const int* rows = ei;
  const int* cols = ei + N_EDGES;

  // ws layout
  size_t off = 0;
  int* gcur = (int*)(ws + off);        off += (size_t)NB * GPAD * 4;            // 80 KB
  float* degw = (float*)(ws + off);    off += (size_t)N_NODES * 4;              // 80 KB (fallback)
  unsigned* xb = (unsigned*)(ws + off);  off += (size_t)N_NODES * (D / 2) * 4;  // 5.12 MB
  unsigned* Wb = (unsigned*)(ws + off);  off += (size_t)D * (D / 2) * 4;        // 32 KB
  uint2* bins = (uint2*)(ws + off);    off += (size_t)NB * CAP2 * 8;            // 7.68 MB
  const size_t main_bytes = off;
  const size_t fallback_bytes = (size_t)NB * GPAD * 4 + (size_t)N_NODES * 4;

  if (ws_size >= main_bytes) {
    zero_kernel<<<(NB * GPAD + 255) / 256, 256, 0, stream>>>(gcur, NB * GPAD);
    castbin_kernel<<<NBLK1 + CASTBLK, 256, 0, stream>>>(x, W, rows, cols, ew,
                                                        xb, Wb, gcur, bins);
    agg_gemm_kernel<<<NB, AGG_T, 0, stream>>>(xb, gcur, bins, Wb, b, out);
  } else if (ws_size >= fallback_bytes) {
    hipMemsetAsync(out, 0, (size_t)N_NODES * D * 4, stream);
    hipMemsetAsync(degw, 0, (size_t)N_NODES * 4, stream);
    scatter_kernel<<<(N_EDGES + 3) / 4, 256, 0, stream>>>(x, rows, cols, ew, out, degw);
    linear_norm_kernel<<<N_NODES / GROWS, 256, 0, stream>>>(W, b, degw, out);
  }
}

// Round 13
// 58.246 us; speedup vs baseline: 1.0193x; 1.0193x over previous
//
#include <hip/hip_runtime.h>
#include <hip/hip_bf16.h>
#include <math.h>

#define N_NODES 20000
#define N_EDGES 640000
#define D 128

#define BSHIFT 4
#define BNODES 16                 // nodes per bucket = waves per agg block
#define NB 1250                   // N_NODES >> BSHIFT
#define CAP2 768                  // per-bucket cap (mean 512, sd ~22.6)
#define AGG_T 1024
#define NBLK1 160
#define CHUNK 4000                // N_EDGES / NBLK1, multiple of 4
#define GPAD 16                   // gcur padded to one 64B line per bucket
#define CASTBLK 625               // N_NODES*D/4 / 1024 exactly

#define GROWS 16                  // fallback linear kernel

typedef __attribute__((ext_vector_type(8))) short bf16x8;
typedef __attribute__((ext_vector_type(4))) float f32x4;

static __device__ __forceinline__ unsigned short f2bf(float f) {
  unsigned u = __float_as_uint(f);
  return (unsigned short)((u + 0x7fffu + ((u >> 16) & 1u)) >> 16);
}
static __device__ __forceinline__ float bflo(unsigned v) {
  return __uint_as_float(v << 16);
}
static __device__ __forceinline__ float bfhi(unsigned v) {
  return __uint_as_float(v & 0xffff0000u);
}

__global__ __launch_bounds__(256) void zero_kernel(int* __restrict__ p, int n) {
  const int i = blockIdx.x * 256 + threadIdx.x;
  if (i < n) p[i] = 0;
}

// ---- fused (1024 thr): blocks [0,NBLK1) bin via LDS counting sort; rest cast ----
__global__ __launch_bounds__(AGG_T) void castbin_kernel(
    const float* __restrict__ x, const float* __restrict__ W,
    const int* __restrict__ rows, const int* __restrict__ cols,
    const float* __restrict__ ew,
    unsigned* __restrict__ xb, unsigned* __restrict__ Wb,
    int* __restrict__ gcur, uint2* __restrict__ bins) {
  __shared__ uint2 stage[CHUNK];   // 32 KB sorted staging
  __shared__ int cnt[NB];          // 5 KB
  __shared__ int lbase[NB];        // 5 KB
  __shared__ int gbase[NB];        // 5 KB
  const int tid = threadIdx.x;
  if (blockIdx.x < NBLK1) {
    // ---- bin: count -> scan -> LDS rank-scatter -> coalesced write-out ----
    const int e0 = blockIdx.x * CHUNK;
    for (int i = tid; i < NB; i += AGG_T) cnt[i] = 0;
    __syncthreads();
    const int4* r4 = reinterpret_cast<const int4*>(rows + e0);
    int4 rv;
    const bool own = tid < CHUNK / 4;   // 1000 int4-slots, 1 per thread
    if (own) {
      rv = r4[tid];
      atomicAdd(&cnt[rv.x >> BSHIFT], 1);
      atomicAdd(&cnt[rv.y >> BSHIFT], 1);
      atomicAdd(&cnt[rv.z >> BSHIFT], 1);
      atomicAdd(&cnt[rv.w >> BSHIFT], 1);
    }
    __syncthreads();
    if (tid < 64) {  // single-wave serial-carry scan over 1250 counters
      int carry = 0;
      for (int c0 = 0; c0 < NB; c0 += 64) {
        const int idx = c0 + tid;
        const int v = (idx < NB) ? cnt[idx] : 0;
        int s = v;
#pragma unroll
        for (int off = 1; off < 64; off <<= 1) {
          const int t = __shfl_up(s, off);
          if (tid >= off) s += t;
        }
        if (idx < NB) lbase[idx] = carry + s - v;
        carry += __shfl(s, 63);
      }
    }
    for (int i = tid; i < NB; i += AGG_T) {
      const int c = cnt[i];
      gbase[i] = c ? atomicAdd(&gcur[i * GPAD], c) : 0;  // one line per bucket
    }
    __syncthreads();
    for (int i = tid; i < NB; i += AGG_T) cnt[i] = 0;
    __syncthreads();
    if (own) {  // rank-scatter into LDS
      const int4 cv = reinterpret_cast<const int4*>(cols + e0)[tid];
      const float4 wv = reinterpret_cast<const float4*>(ew + e0)[tid];
      const int rr[4] = {rv.x, rv.y, rv.z, rv.w};
      const int cc[4] = {cv.x, cv.y, cv.z, cv.w};
      const float ww[4] = {wv.x, wv.y, wv.z, wv.w};
#pragma unroll
      for (int u = 0; u < 4; ++u) {
        const int b = rr[u] >> BSHIFT;
        const int r = atomicAdd(&cnt[b], 1);
        stage[lbase[b] + r] =
            make_uint2(((unsigned)rr[u] << 16) | (unsigned)cc[u],
                       __float_as_uint(ww[u]));
      }
    }
    __syncthreads();
    // write-out: adjacent lanes -> adjacent slots -> coalesced bucket runs
    for (int i = tid; i < CHUNK; i += AGG_T) {
      const uint2 e = stage[i];
      const int b = (int)(e.x >> 20);  // row>>4
      const int p = gbase[b] + (i - lbase[b]);
      if (p < CAP2) bins[(size_t)b * CAP2 + p] = e;
    }
  } else {
    // ---------------- cast ----------------
    const int i = (blockIdx.x - NBLK1) * AGG_T + tid;  // one float4 per thread
    {
      const float4 v = *reinterpret_cast<const float4*>(&x[(size_t)i * 4]);
      uint2 o;
      o.x = (unsigned)f2bf(v.x) | ((unsigned)f2bf(v.y) << 16);
      o.y = (unsigned)f2bf(v.z) | ((unsigned)f2bf(v.w) << 16);
      *reinterpret_cast<uint2*>(&xb[(size_t)i * 2]) = o;
    }
    if (i < D * D / 4) {
      const float4 v = *reinterpret_cast<const float4*>(&W[(size_t)i * 4]);
      uint2 o;
      o.x = (unsigned)f2bf(v.x) | ((unsigned)f2bf(v.y) << 16);
      o.y = (unsigned)f2bf(v.z) | ((unsigned)f2bf(v.w) << 16);
      *reinterpret_cast<uint2*>(&Wb[(size_t)i * 2]) = o;
    }
  }
}

// ---- fused agg+gemm, one block per 16-node bucket, ONE WAVE PER NODE ----
__global__ __launch_bounds__(AGG_T) void agg_gemm_kernel(
    const unsigned* __restrict__ xb, const int* __restrict__ gcur,
    const uint2* __restrict__ bins, const unsigned* __restrict__ Wb,
    const float* __restrict__ bias, float* __restrict__ out) {
  __shared__ uint2 list[CAP2];             // 6 KB
  __shared__ unsigned aggls[BNODES * 64];  // 4 KB, swizzled bf16 means
  __shared__ int cnt[BNODES];
  __shared__ int base[BNODES];
  __shared__ float degls[BNODES];
  const int b = blockIdx.x;
  const int tid = threadIdx.x;
  const int n = min(gcur[b * GPAD], CAP2);
  if (tid < BNODES) cnt[tid] = 0;
  __syncthreads();

  // rank: one edge per thread, single pass (n <= 768 < 1024)
  uint2 ev;
  int rk = -1, rl = 0;
  if (tid < n) {
    ev = bins[(size_t)b * CAP2 + tid];
    rl = (int)(ev.x >> 16) & 15;
    rk = atomicAdd(&cnt[rl], 1);
  }
  __syncthreads();
  if (tid < 64) {  // wave-parallel inclusive scan over 16 counters
    const int c = (tid < BNODES) ? cnt[tid] : 0;
    int s = c;
#pragma unroll
    for (int off = 1; off < BNODES; off <<= 1) {
      const int t = __shfl_up(s, off);
      if (tid >= off) s += t;
    }
    if (tid < BNODES) base[tid] = s - c;
  }
  __syncthreads();
  if (rk >= 0) list[base[rl] + rk] = ev;
  __syncthreads();

  // gather: 16 waves, wave w owns node w; lane = (quarter q4, fidx);
  // lane loads uint4 = feats 8f..8f+7 of edge (k + u*4 + q4): 4 edges/wave-load.
  const int wv = tid >> 6, lane = tid & 63;
  const int q4 = lane >> 4, fidx = lane & 15;
  {
    const int s = base[wv];
    const int ke = s + cnt[wv];
    float a[8] = {0.f, 0.f, 0.f, 0.f, 0.f, 0.f, 0.f, 0.f};
    float dw = 0.f;
    for (int k = s; k < ke; k += 32) {  // 32 edges in flight per wave
      uint4 v[8];
      float w[8];
#pragma unroll
      for (int u = 0; u < 8; ++u) {
        int idx = k + u * 4 + q4;
        const bool ok = idx < ke;
        if (!ok) idx = ke - 1;          // loop entered => ke >= s+1, safe
        const uint2 e = list[idx];
        w[u] = ok ? __uint_as_float(e.y) : 0.f;
        v[u] = *reinterpret_cast<const uint4*>(
            &xb[(size_t)(e.x & 0xffffu) * (D / 2) + fidx * 4]);
      }
#pragma unroll
      for (int u = 0; u < 8; ++u) {
        a[0] += bflo(v[u].x) * w[u]; a[1] += bfhi(v[u].x) * w[u];
        a[2] += bflo(v[u].y) * w[u]; a[3] += bfhi(v[u].y) * w[u];
        a[4] += bflo(v[u].z) * w[u]; a[5] += bfhi(v[u].z) * w[u];
        a[6] += bflo(v[u].w) * w[u]; a[7] += bfhi(v[u].w) * w[u];
        dw += w[u];
      }
    }
    // combine the 4 quarters
#pragma unroll
    for (int j = 0; j < 8; ++j) {
      a[j] += __shfl_xor(a[j], 16);
      a[j] += __shfl_xor(a[j], 32);
    }
    dw += __shfl_xor(dw, 16);
    dw += __shfl_xor(dw, 32);
    const float dinv = dw > 0.f ? 1.f / dw : 0.f;
    if (lane == 0) degls[wv] = dw;
    if (q4 == 0) {  // lanes 0-15 store the mean, swizzled, uint4 (16B aligned)
      uint4 o;
      o.x = (unsigned)f2bf(a[0] * dinv) | ((unsigned)f2bf(a[1] * dinv) << 16);
      o.y = (unsigned)f2bf(a[2] * dinv) | ((unsigned)f2bf(a[3] * dinv) << 16);
      o.z = (unsigned)f2bf(a[4] * dinv) | ((unsigned)f2bf(a[5] * dinv) << 16);
      o.w = (unsigned)f2bf(a[6] * dinv) | ((unsigned)f2bf(a[7] * dinv) << 16);
      *reinterpret_cast<uint4*>(
          &aggls[wv * 64 + ((fidx * 4) ^ ((wv & 7) << 2))]) = o;
    }
  }
  __syncthreads();

  // GEMM + normalize: wave 0 only, 16-row tile (R7-verified body)
  if (wv != 0) return;
  const int arow = lane & 15;               // local row 0..15
  const int koff = (lane >> 4) * 4;

  bf16x8 afr[4];
#pragma unroll
  for (int kk = 0; kk < 4; ++kk) {
    const int wbase = (kk * 16 + koff) ^ ((arow & 7) << 2);
    union { uint4 u; bf16x8 v; } cv;
    cv.u = *reinterpret_cast<const uint4*>(&aggls[arow * 64 + wbase]);
    afr[kk] = cv.v;
  }

  f32x4 acc[8];
#pragma unroll
  for (int t = 0; t < 8; ++t) {
    const int o = t * 16 + (lane & 15);
    f32x4 c = {0.f, 0.f, 0.f, 0.f};
#pragma unroll
    for (int kk = 0; kk < 4; ++kk) {
      union { uint4 u; bf16x8 v; } cv;
      cv.u = *reinterpret_cast<const uint4*>(
          &Wb[(size_t)o * (D / 2) + kk * 16 + koff]);
      c = __builtin_amdgcn_mfma_f32_16x16x32_bf16(afr[kk], cv.v, c, 0, 0, 0);
    }
    acc[t] = c;
  }

  float ss[4] = {0.f, 0.f, 0.f, 0.f};
#pragma unroll
  for (int t = 0; t < 8; ++t) {
    const float bc = bias[t * 16 + (lane & 15)];
#pragma unroll
    for (int r = 0; r < 4; ++r) {
      const float y = acc[t][r] + bc;
      acc[t][r] = y;
      ss[r] += y * y;
    }
  }
#pragma unroll
  for (int r = 0; r < 4; ++r) {
#pragma unroll
    for (int off = 1; off < 16; off <<= 1)
      ss[r] += __shfl_xor(ss[r], off);
  }
  const int row0 = b * BNODES;
  float scale[4];
#pragma unroll
  for (int r = 0; r < 4; ++r) {
    const int lrow = (lane >> 4) * 4 + r;
    const float dw = degls[lrow];
    scale[r] = (dw > 0.f) ? 1.f / fmaxf(sqrtf(ss[r]), 1e-12f) : 0.f;
  }
#pragma unroll
  for (int t = 0; t < 8; ++t) {
#pragma unroll
    for (int r = 0; r < 4; ++r) {
      const int lrow = (lane >> 4) * 4 + r;
      out[(size_t)(row0 + lrow) * D + t * 16 + (lane & 15)] =
          acc[t][r] * scale[r];
    }
  }
}

// ---- fallback path (tiny ws): f32 scatter + f32 GEMV/norm ----
__global__ __launch_bounds__(256) void scatter_kernel(
    const float* __restrict__ x, const int* __restrict__ rows,
    const int* __restrict__ cols, const float* __restrict__ ew,
    float* __restrict__ out, float* __restrict__ degw) {
  const int e = blockIdx.x * 4 + (threadIdx.x >> 6);
  const int lane = threadIdx.x & 63;
  if (e >= N_EDGES) return;
  const int r = rows[e];
  const int c = cols[e];
  const float w = ew[e];
  const float2 v = *reinterpret_cast<const float2*>(&x[(size_t)c * D + lane * 2]);
  atomicAdd(&out[(size_t)r * D + lane * 2], v.x * w);
  atomicAdd(&out[(size_t)r * D + lane * 2 + 1], v.y * w);
  if (lane == 0) atomicAdd(&degw[r], w);
}

__global__ __launch_bounds__(256) void linear_norm_kernel(
    const float* __restrict__ W, const float* __restrict__ b,
    const float* __restrict__ degw, float* __restrict__ out) {
  __shared__ float Ws[D][D + 1];
  __shared__ float xs[GROWS][D];
  __shared__ float dws[GROWS];
  const int tid = threadIdx.x;
  const int row0 = blockIdx.x * GROWS;
  for (int idx = tid; idx < D * D; idx += 256)
    Ws[idx >> 7][idx & 127] = W[idx];
  if (tid < GROWS) dws[tid] = degw[row0 + tid];
  __syncthreads();
  for (int idx = tid; idx < GROWS * D; idx += 256) {
    const int r = idx >> 7;
    const float dw = dws[r];
    const float dinv = dw > 0.f ? 1.f / dw : 0.f;
    xs[r][idx & 127] = out[(size_t)(row0 + r) * D + (idx & 127)] * dinv;
  }
  __syncthreads();
  const int o = tid & 127;
  const int rh = tid >> 7;
  float acc[GROWS / 2];
#pragma unroll
  for (int j = 0; j < GROWS / 2; ++j) acc[j] = 0.f;
  for (int k = 0; k < D; ++k) {
    const float wv = Ws[o][k];
#pragma unroll
    for (int j = 0; j < GROWS / 2; ++j)
      acc[j] += xs[rh + 2 * j][k] * wv;
  }
  const float bias = b[o];
  __syncthreads();
#pragma unroll
  for (int j = 0; j < GROWS / 2; ++j)
    xs[rh + 2 * j][o] = acc[j] + bias;
  __syncthreads();
  const int w = tid >> 6, lane = tid & 63;
#pragma unroll
  for (int q = 0; q < 4; ++q) {
    const int r = w * 4 + q;
    const float2 v = *reinterpret_cast<const float2*>(&xs[r][lane * 2]);
    float ss = v.x * v.x + v.y * v.y;
#pragma unroll
    for (int off = 1; off < 64; off <<= 1) ss += __shfl_xor(ss, off);
    const float dw = dws[r];
    const float scale = (dw > 0.f) ? 1.f / fmaxf(sqrtf(ss), 1e-12f) : 0.f;
    *reinterpret_cast<float2*>(&out[(size_t)(row0 + r) * D + lane * 2]) =
        make_float2(v.x * scale, v.y * scale);
  }
}

extern "C" void kernel_launch(void* const* d_in, const int* in_sizes, int n_in,
                              void* d_out, int out_size, void* d_ws, size_t ws_size,
                              hipStream_t stream) {
  const float* x  = (const float*)d_in[0];
  const int*   ei = (const int*)d_in[1];
  const float* ew = (const float*)d_in[2];
  const float* W  = (const float*)d_in[3];
  const float* b  = (const float*)d_in[4];
  float* out = (float*)d_out;
  char* ws = (char*)d_ws;

  const int* rows = ei;
  const int* cols = ei + N_EDGES;

  // ws layout
  size_t off = 0;
  int* gcur = (int*)(ws + off);        off += (size_t)NB * GPAD * 4;            // 80 KB
  float* degw = (float*)(ws + off);    off += (size_t)N_NODES * 4;              // 80 KB (fallback)
  unsigned* xb = (unsigned*)(ws + off);  off += (size_t)N_NODES * (D / 2) * 4;  // 5.12 MB
  unsigned* Wb = (unsigned*)(ws + off);  off += (size_t)D * (D / 2) * 4;        // 32 KB
  uint2* bins = (uint2*)(ws + off);    off += (size_t)NB * CAP2 * 8;            // 7.68 MB
  const size_t main_bytes = off;
  const size_t fallback_bytes = (size_t)NB * GPAD * 4 + (size_t)N_NODES * 4;

  if (ws_size >= main_bytes) {
    zero_kernel<<<(NB * GPAD + 255) / 256, 256, 0, stream>>>(gcur, NB * GPAD);
    castbin_kernel<<<NBLK1 + CASTBLK, AGG_T, 0, stream>>>(x, W, rows, cols, ew,
                                                          xb, Wb, gcur, bins);
    agg_gemm_kernel<<<NB, AGG_T, 0, stream>>>(xb, gcur, bins, Wb, b, out);
  } else if (ws_size >= fallback_bytes) {
    hipMemsetAsync(out, 0, (size_t)N_NODES * D * 4, stream);
    hipMemsetAsync(degw, 0, (size_t)N_NODES * 4, stream);
    scatter_kernel<<<(N_EDGES + 3) / 4, 256, 0, stream>>>(x, rows, cols, ew, out, degw);
    linear_norm_kernel<<<N_NODES / GROWS, 256, 0, stream>>>(W, b, degw, out);
  }
}